// Round 4
// baseline (33254.144 us; speedup 1.0000x reference)
//
#include <hip/hip_runtime.h>
#include <math.h>

// Persistent cooperative seq2seq, round 4.
// r3 lessons: (a) scattered sc1 stores caused 16x write amplification
// (WRITE_SIZE 4.17GB) -> all cross-block stores now lane-coalesced;
// (b) single release line caused barrier convoy -> 8 spread release lines,
// 256B-spaced arrive slots, sleep backoff; (c) 4B h loads -> 8B, 8-deep.

#define NBLK 256
#define NTHR 512
#define SEQ  200
#define TST  150
#define HID  512
#define G4   2048
#define VOC  231
#define EMBD 256
#define NB   256
#define BVO  (NB*VOC)   // 59136
#define PSTR 67         // LDS pad stride (floats)

__device__ __forceinline__ float sigf(float x){ return 1.0f/(1.0f+expf(-x)); }

__device__ __forceinline__ float agld(const float* p){
  return __hip_atomic_load(p, __ATOMIC_RELAXED, __HIP_MEMORY_SCOPE_AGENT);
}
__device__ __forceinline__ void agst(float* p, float v){
  __hip_atomic_store(p, v, __ATOMIC_RELAXED, __HIP_MEMORY_SCOPE_AGENT);
}
__device__ __forceinline__ float2 ld2(const float* p){
  unsigned long long u = __hip_atomic_load((unsigned long long*)p,
      __ATOMIC_RELAXED, __HIP_MEMORY_SCOPE_AGENT);
  union { unsigned long long v; float2 f; } c; c.v = u; return c.f;
}

// ---- grid barrier: 256B-spaced arrive slots, block0 aggregates, 8 release lines ----
__device__ __forceinline__ void gsync(int* bar, int e) {
  __syncthreads();
  if (threadIdx.x == 0)
    __hip_atomic_store(&bar[blockIdx.x*64], e, __ATOMIC_RELAXED, __HIP_MEMORY_SCOPE_AGENT);
  if (blockIdx.x == 0) {
    if (threadIdx.x < NBLK) {
      while (__hip_atomic_load(&bar[threadIdx.x*64], __ATOMIC_RELAXED,
                               __HIP_MEMORY_SCOPE_AGENT) < e)
        __builtin_amdgcn_s_sleep(1);
    }
    __syncthreads();
    if (threadIdx.x < 8)
      __hip_atomic_store(&bar[16384 + threadIdx.x*64], e, __ATOMIC_RELAXED,
                         __HIP_MEMORY_SCOPE_AGENT);
  } else {
    if (threadIdx.x == 0) {
      while (__hip_atomic_load(&bar[16384 + (blockIdx.x & 7)*64], __ATOMIC_RELAXED,
                               __HIP_MEMORY_SCOPE_AGENT) < e)
        __builtin_amdgcn_s_sleep(3);
    }
    __syncthreads();
  }
}

// ---- encoder step: block = 32 rows {g*512+kb*8+u} x 64 b. 8 waves = K-eighths. ----
__device__ void encStep(const float* __restrict__ hin, float* __restrict__ hout,
    float* __restrict__ cOut, const float* __restrict__ eWhh,
    const float* __restrict__ wcomb, const float* __restrict__ bcomb,
    const float* __restrict__ trainT, int t, int last, float& cE, float* smem)
{
  const int tid = threadIdx.x, bid = blockIdx.x;
  const int kb = bid >> 2, bg = bid & 3;
  const int q = tid >> 6, lane = tid & 63;
  const float* hb = hin + (size_t)(bg*64 + lane)*HID + q*64;
  float acc[32];
#pragma unroll
  for (int r = 0; r < 32; ++r) acc[r] = 0.f;
  float2 hv[8], cu[8];
#pragma unroll
  for (int u = 0; u < 8; ++u) hv[u] = ld2(hb + 2*u);
  for (int c = 0; c < 4; ++c) {
#pragma unroll
    for (int u = 0; u < 8; ++u) cu[u] = hv[u];
    if (c < 3) {
#pragma unroll
      for (int u = 0; u < 8; ++u) hv[u] = ld2(hb + (c+1)*16 + 2*u);
    }
    const int kk = q*64 + c*16;
#pragma unroll
    for (int u = 0; u < 8; ++u) {
#pragma unroll
      for (int r = 0; r < 32; ++r) {
        const float* wr = eWhh + ((size_t)(r>>3)*512 + kb*8 + (r&7))*HID + kk + 2*u;
        acc[r] += wr[0]*cu[u].x + wr[1]*cu[u].y;
      }
    }
  }
#pragma unroll
  for (int r = 0; r < 32; ++r) smem[(q*32 + r)*PSTR + lane] = acc[r];
  __syncthreads();
  // pointwise: thread -> (bb = tid>>3, u = tid&7); k = kb*8+u, b = bg*64+bb
  const int bb = tid >> 3, u = tid & 7;
  const int k = kb*8 + u;
  const int gb = bg*64 + bb;
  float x0 = trainT[t*512 + gb];
  float x1 = trainT[t*512 + 256 + gb];
  float pre[4];
#pragma unroll
  for (int g = 0; g < 4; ++g) {
    float s = 0.f;
#pragma unroll
    for (int qq = 0; qq < 8; ++qq) s += smem[(qq*32 + g*8 + u)*PSTR + bb];
    int j = g*512 + k;
    pre[g] = s + wcomb[2*j]*x0 + wcomb[2*j+1]*x1 + bcomb[j];
  }
  float ii=sigf(pre[0]), ff=sigf(pre[1]), gg=tanhf(pre[2]), oo=sigf(pre[3]);
  cE = ff*cE + ii*gg;
  agst(hout + (size_t)gb*HID + k, oo*tanhf(cE));
  if (last) agst(cOut + (size_t)gb*HID + k, cE);
}

// ---- decoder P: rows j0..j0+39 of [dWhh; W1] (unified WU), 64 b. GH->[b][j], o1->[b][k] ----
__device__ void phaseP(const float* __restrict__ hin, float* __restrict__ GHT,
    float* __restrict__ o1T, const float* __restrict__ WU,
    const float* __restrict__ b1, float* smem)
{
  const int tid = threadIdx.x, bid = blockIdx.x;
  const int rg = bid >> 2, bg = bid & 3;
  const int j0 = rg*40;
  const int q = tid >> 6, lane = tid & 63;
  const float* hb = hin + (size_t)(bg*64 + lane)*HID + q*64;
  const float* wb = WU + (size_t)j0*HID;
  float acc[40];
#pragma unroll
  for (int r = 0; r < 40; ++r) acc[r] = 0.f;
  float2 hv[8], cu[8];
#pragma unroll
  for (int u = 0; u < 8; ++u) hv[u] = ld2(hb + 2*u);
  for (int c = 0; c < 4; ++c) {
#pragma unroll
    for (int u = 0; u < 8; ++u) cu[u] = hv[u];
    if (c < 3) {
#pragma unroll
      for (int u = 0; u < 8; ++u) hv[u] = ld2(hb + (c+1)*16 + 2*u);
    }
    const int kk = q*64 + c*16;
#pragma unroll
    for (int u = 0; u < 8; ++u) {
#pragma unroll
      for (int r = 0; r < 40; ++r) {
        const float* wr = wb + (size_t)r*HID + kk + 2*u;
        acc[r] += wr[0]*cu[u].x + wr[1]*cu[u].y;
      }
    }
  }
#pragma unroll
  for (int r = 0; r < 40; ++r) smem[(q*40 + r)*PSTR + lane] = acc[r];
  __syncthreads();
  // write: thread -> (bb = tid>>3, jo = tid&7), 5 rows each (r = jo+8u)
  const int bb = tid >> 3, jo = tid & 7;
  const int gb = bg*64 + bb;
#pragma unroll
  for (int u = 0; u < 5; ++u) {
    int r = jo + 8*u;
    float s = 0.f;
#pragma unroll
    for (int qq = 0; qq < 8; ++qq) s += smem[(qq*40 + r)*PSTR + bb];
    int j = j0 + r;
    if (j < G4) agst(GHT + (size_t)gb*G4 + j, s);
    else        agst(o1T + (size_t)gb*HID + (j - G4), fmaxf(s + b1[j - G4], 0.f));
  }
}

// ---- decoder Q (blocks 0..127, 2 batch each): o2 + argmax + out row + LSTM pointwise ----
__device__ void phaseQ(int i, const float* __restrict__ GHT,
    const float* __restrict__ o1T, const float* __restrict__ GIH,
    const float* __restrict__ W2, const float* __restrict__ b2,
    const int* __restrict__ target, const float* __restrict__ cET,
    float* __restrict__ hnxt, float* __restrict__ out,
    float& cA, float& cB,
    float* o1sA, float* o1sB, float* o2A, float* o2B, float* amv, int* ami)
{
  int tid = threadIdx.x, bid = blockIdx.x;
  if (bid >= 128) return;
  int bA = 2*bid, bB = bA + 1;
  int tokA, tokB;
  if (i == 0) {
    tokA = target[bA*TST];
    tokB = target[bB*TST];
    cA = agld(cET + (size_t)bA*HID + tid);
    cB = agld(cET + (size_t)bB*HID + tid);
  } else {
    o1sA[tid] = agld(o1T + (size_t)bA*HID + tid);
    o1sB[tid] = agld(o1T + (size_t)bB*HID + tid);
    __syncthreads();
    if (tid < 2*VOC) {
      int row = tid >> 1, half = tid & 1;
      const float4* w4 = (const float4*)(W2 + (size_t)row*HID + half*256);
      const float4* aA = (const float4*)(o1sA + half*256);
      const float4* aB = (const float4*)(o1sB + half*256);
      float sA = 0.f, sB = 0.f;
#pragma unroll 8
      for (int qq = 0; qq < 64; ++qq) {
        float4 w = w4[qq], a = aA[qq], bb2 = aB[qq];
        sA += w.x*a.x + w.y*a.y + w.z*a.z + w.w*a.w;
        sB += w.x*bb2.x + w.y*bb2.y + w.z*bb2.z + w.w*bb2.w;
      }
      sA += __shfl_xor(sA, 1);
      sB += __shfl_xor(sB, 1);
      if (half == 0) {
        o2A[row] = fmaxf(sA + b2[row], 0.f);
        o2B[row] = fmaxf(sB + b2[row], 0.f);
      }
    }
    __syncthreads();
    {
      int tt = tid & 255;
      int base = (tid < 256) ? 0 : 256;
      const float* o2s = (tid < 256) ? o2A : o2B;
      amv[base + tt] = (tt < VOC) ? o2s[tt] : -3.0e38f;
      ami[base + tt] = tt;
      __syncthreads();
      for (int off = 128; off; off >>= 1) {
        if (tt < off) {
          float vo = amv[base + tt + off]; int io = ami[base + tt + off];
          if (vo > amv[base + tt] || (vo == amv[base + tt] && io < ami[base + tt])) {
            amv[base + tt] = vo; ami[base + tt] = io;
          }
        }
        __syncthreads();
      }
    }
    tokA = ami[0]; tokB = ami[256];
    if (tid < VOC)
      out[(size_t)i*BVO + (size_t)bA*VOC + tid] = o2A[tid];               // plain store
    else if (tid >= 256 && tid < 256 + VOC)
      out[(size_t)i*BVO + (size_t)bB*VOC + (tid-256)] = o2B[tid-256];     // plain store
    if (i == TST-1) return;
  }
  float preA[4], preB[4];
#pragma unroll
  for (int g = 0; g < 4; ++g) {
    int j = g*512 + tid;
    preA[g] = agld(GHT + (size_t)bA*G4 + j) + GIH[(size_t)tokA*G4 + j];
    preB[g] = agld(GHT + (size_t)bB*G4 + j) + GIH[(size_t)tokB*G4 + j];
  }
  {
    float ii=sigf(preA[0]), ff=sigf(preA[1]), gg=tanhf(preA[2]), oo=sigf(preA[3]);
    cA = ff*cA + ii*gg;
    agst(hnxt + (size_t)bA*HID + tid, oo*tanhf(cA));
  }
  {
    float ii=sigf(preB[0]), ff=sigf(preB[1]), gg=tanhf(preB[2]), oo=sigf(preB[3]);
    cB = ff*cB + ii*gg;
    agst(hnxt + (size_t)bB*HID + tid, oo*tanhf(cB));
  }
}

__global__ __launch_bounds__(NTHR, 2) void k_all(
    const float* __restrict__ train, const int* __restrict__ target,
    const float* __restrict__ fcW,  const float* __restrict__ fcb,
    const float* __restrict__ eWih, const float* __restrict__ eWhh,
    const float* __restrict__ ebih, const float* __restrict__ ebhh,
    const float* __restrict__ emb,  const float* __restrict__ dWih,
    const float* __restrict__ dWhh, const float* __restrict__ dbih,
    const float* __restrict__ dbhh, const float* __restrict__ W1,
    const float* __restrict__ b1,   const float* __restrict__ W2,
    const float* __restrict__ b2,   float* __restrict__ out,
    void* __restrict__ ws)
{
  __shared__ float smem[21440];           // enc 8*32*67 / P 8*40*67 / pre emb row
  __shared__ float o1sA[512], o1sB[512];
  __shared__ float o2A[VOC+9], o2B[VOC+9];
  __shared__ float amv[512];
  __shared__ int   ami[512];

  int* bar     = (int*)ws;                // 32768 ints, host-memset to 0
  float* fws   = (float*)ws + 32768;
  float* wcomb = fws;                     // 4096
  float* bcomb = wcomb + 4096;            // 2048
  float* GIH   = bcomb + 2048;            // 473088
  float* WU    = GIH + 473088;            // 1310720 = [dWhh(2048); W1(512)] rows x 512
  float* hTA   = WU + 1310720;            // 131072  [b][k]
  float* hTB   = hTA + 131072;            // 131072
  float* cET   = hTB + 131072;            // 131072  [b][k]
  float* o1T   = cET + 131072;            // 131072  [b][k]
  float* GHT   = o1T + 131072;            // 524288  [b][j]
  float* trainT= GHT + 524288;            // 102400  [t][f][b]

  int tid = threadIdx.x, bid = blockIdx.x;
  int ep = 1;

  // ================= pre-phase =================
  {
    int tg = bid * NTHR + tid;            // 0..131071
    agst(&hTA[tg], 0.f);
    if (tg < BVO) out[tg] = 0.f;          // plain; unique writer
    if (tg < SEQ*2*NB) {
      int t = tg >> 9, f = (tg >> 8) & 1, b = tg & 255;
      agst(&trainT[tg], train[((size_t)b*SEQ + t)*2 + f]);
    }
    if (tg < G4) {                        // fold enc FC into input weights
      const float* wrow = eWih + (size_t)tg * EMBD;
      float s0=0.f, s1=0.f, sb=0.f;
      for (int k2 = 0; k2 < EMBD; k2 += 4) {
        float4 w4 = *(const float4*)(wrow + k2);
        s0 += w4.x*fcW[2*k2]   + w4.y*fcW[2*k2+2] + w4.z*fcW[2*k2+4] + w4.w*fcW[2*k2+6];
        s1 += w4.x*fcW[2*k2+1] + w4.y*fcW[2*k2+3] + w4.z*fcW[2*k2+5] + w4.w*fcW[2*k2+7];
        sb += w4.x*fcb[k2]     + w4.y*fcb[k2+1]   + w4.z*fcb[k2+2]   + w4.w*fcb[k2+3];
      }
      agst(&wcomb[2*tg], s0);
      agst(&wcomb[2*tg+1], s1);
      agst(&bcomb[tg], sb + ebih[tg] + ebhh[tg]);
    }
    // unified decoder weight matrix WU = [dWhh; W1]
    for (int n = 0; n < 10; ++n) {
      int idx = n*131072 + tg;
      if (idx < 1310720) {
        int j = idx >> 9, k = idx & 511;
        float v = (j < G4) ? dWhh[(size_t)j*HID + k] : W1[(size_t)(j-G4)*HID + k];
        agst(&WU[idx], v);
      }
    }
    __syncthreads();
    if (bid < VOC) {                      // GIH[v][j] = emb[v].dWih[j] + biases
      if (tid < EMBD) smem[tid] = emb[(size_t)bid*EMBD + tid];
      __syncthreads();
      for (int u = 0; u < 4; ++u) {
        int j = u*512 + tid;
        const float* wrow = dWih + (size_t)j*EMBD;
        float s = 0.f;
        for (int k2 = 0; k2 < EMBD; k2 += 4) {
          float4 w4 = *(const float4*)(wrow + k2);
          s += smem[k2]*w4.x + smem[k2+1]*w4.y + smem[k2+2]*w4.z + smem[k2+3]*w4.w;
        }
        agst(&GIH[(size_t)bid*G4 + j], s + dbih[j] + dbhh[j]);
      }
    }
  }
  gsync(bar, ep); ep++;

  // ================= encoder: 200 steps =================
  {
    float cE = 0.f;
    const float* hin = hTA; float* hout = hTB;
    for (int t = 0; t < SEQ; ++t) {
      encStep(hin, hout, cET, eWhh, wcomb, bcomb, trainT, t, t == SEQ-1, cE, smem);
      gsync(bar, ep); ep++;
      const float* tmp = hin; hin = hout; hout = (float*)tmp;
    }
  }
  // h_enc in hTA

  // ================= decoder =================
  float cA = 0.f, cB = 0.f;
  phaseP(hTA, GHT, o1T, WU, b1, smem);
  gsync(bar, ep); ep++;
  phaseQ(0, GHT, o1T, GIH, W2, b2, target, cET, hTB, out, cA, cB,
         o1sA, o1sB, o2A, o2B, amv, ami);
  gsync(bar, ep); ep++;
  for (int i = 1; i < TST; ++i) {
    const float* cur = (i & 1) ? hTB : hTA;
    float* nxt      = (i & 1) ? hTA : hTB;
    phaseP(cur, GHT, o1T, WU, b1, smem);
    gsync(bar, ep); ep++;
    phaseQ(i, GHT, o1T, GIH, W2, b2, target, cET, nxt, out, cA, cB,
           o1sA, o1sB, o2A, o2B, amv, ami);
    if (i < TST-1) { gsync(bar, ep); ep++; }
  }
}

extern "C" void kernel_launch(void* const* d_in, const int* in_sizes, int n_in,
                              void* d_out, int out_size, void* d_ws, size_t ws_size,
                              hipStream_t stream) {
  const float* train = (const float*)d_in[0];
  const int*   target= (const int*)  d_in[1];
  const float* fcW   = (const float*)d_in[2];
  const float* fcb   = (const float*)d_in[3];
  const float* eWih  = (const float*)d_in[4];
  const float* eWhh  = (const float*)d_in[5];
  const float* ebih  = (const float*)d_in[6];
  const float* ebhh  = (const float*)d_in[7];
  const float* emb   = (const float*)d_in[8];
  const float* dWih  = (const float*)d_in[9];
  const float* dWhh  = (const float*)d_in[10];
  const float* dbih  = (const float*)d_in[11];
  const float* dbhh  = (const float*)d_in[12];
  const float* W1    = (const float*)d_in[13];
  const float* b1    = (const float*)d_in[14];
  const float* W2    = (const float*)d_in[15];
  const float* b2    = (const float*)d_in[16];
  float* out = (float*)d_out;
  void* ws = d_ws;

  size_t need = (size_t)32768*4 + (size_t)2940928*4;   // ~11.9 MB
  if (ws_size < need) return;  // fail visibly

  hipMemsetAsync(d_ws, 0, 32768 * sizeof(int), stream);  // barrier slots

  void* args[] = { (void*)&train, (void*)&target, (void*)&fcW, (void*)&fcb,
                   (void*)&eWih, (void*)&eWhh, (void*)&ebih, (void*)&ebhh,
                   (void*)&emb, (void*)&dWih, (void*)&dWhh, (void*)&dbih,
                   (void*)&dbhh, (void*)&W1, (void*)&b1, (void*)&W2,
                   (void*)&b2, (void*)&out, (void*)&ws };
  hipError_t err = hipLaunchCooperativeKernel(
      reinterpret_cast<void*>(k_all), dim3(NBLK), dim3(NTHR), args, 0, stream);
  if (err != hipSuccess) {
    // fallback: plain launch; 256 blocks, 1 block/CU -> all co-resident.
    k_all<<<dim3(NBLK), dim3(NTHR), 0, stream>>>(
        train, target, fcW, fcb, eWih, eWhh, ebih, ebhh, emb, dWih, dWhh,
        dbih, dbhh, W1, b1, W2, b2, out, ws);
  }
}

// Round 5
// 17627.811 us; speedup vs baseline: 1.8865x; 1.8865x over previous
//
#include <hip/hip_runtime.h>
#include <math.h>

// Persistent cooperative seq2seq, round 5.
// r4 lessons: agent(sc1) ops bypass AND never fill L2 -> strided access gets
// full line-amplification every time. Fix: [k][b] layout, lane=b everywhere,
// 8B loads LDS-staged in 32-deep bursts. GH kept block-local in LDS (producer
// block == consumer block). One-time agent acquire fence makes ws tables
// safely cacheable (normal loads) after the pre-phase.

#define NBLK 256
#define NTHR 512
#define SEQ  200
#define TST  150
#define HID  512
#define G4   2048
#define VOC  231
#define EMBD 256
#define NB   256
#define BVO  (NB*VOC)   // 59136

__device__ __forceinline__ float sigf(float x){ return 1.0f/(1.0f+expf(-x)); }

__device__ __forceinline__ float agld(const float* p){
  return __hip_atomic_load((float*)p, __ATOMIC_RELAXED, __HIP_MEMORY_SCOPE_AGENT);
}
__device__ __forceinline__ void agst(float* p, float v){
  __hip_atomic_store(p, v, __ATOMIC_RELAXED, __HIP_MEMORY_SCOPE_AGENT);
}
__device__ __forceinline__ unsigned long long agld8(const void* p){
  return __hip_atomic_load((unsigned long long*)p, __ATOMIC_RELAXED,
                           __HIP_MEMORY_SCOPE_AGENT);
}
__device__ __forceinline__ int agldi(const int* p){
  return __hip_atomic_load((int*)p, __ATOMIC_RELAXED, __HIP_MEMORY_SCOPE_AGENT);
}
__device__ __forceinline__ void agsti(int* p, int v){
  __hip_atomic_store(p, v, __ATOMIC_RELAXED, __HIP_MEMORY_SCOPE_AGENT);
}

// grid barrier: 256B-spaced arrive slots, block0 aggregates, 8 release lines.
// relaxed flags are sound: __syncthreads drains each wave's vmcnt, and sc1
// stores are write-through to the coherence point.
__device__ __forceinline__ void gsync(int* bar, int e) {
  __syncthreads();
  if (threadIdx.x == 0)
    __hip_atomic_store(&bar[blockIdx.x*64], e, __ATOMIC_RELAXED, __HIP_MEMORY_SCOPE_AGENT);
  if (blockIdx.x == 0) {
    if (threadIdx.x < NBLK) {
      while (__hip_atomic_load(&bar[threadIdx.x*64], __ATOMIC_RELAXED,
                               __HIP_MEMORY_SCOPE_AGENT) < e)
        __builtin_amdgcn_s_sleep(1);
    }
    __syncthreads();
    if (threadIdx.x < 8)
      __hip_atomic_store(&bar[16384 + threadIdx.x*64], e, __ATOMIC_RELAXED,
                         __HIP_MEMORY_SCOPE_AGENT);
  } else {
    if (threadIdx.x == 0) {
      while (__hip_atomic_load(&bar[16384 + (blockIdx.x & 7)*64], __ATOMIC_RELAXED,
                               __HIP_MEMORY_SCOPE_AGENT) < e)
        __builtin_amdgcn_s_sleep(1);
    }
    __syncthreads();
  }
}

// stage h[512][bg*64..+64] (global [k][256]) -> hst[512][64]. 32 8B loads/thread,
// issued in two 16-deep batches for MLP.
__device__ __forceinline__ void stageH(const float* h, int bg, int tid, float* hst){
  const char* base = (const char*)(h + bg*64);
  unsigned long long* d = (unsigned long long*)hst;
  unsigned long long v[16];
#pragma unroll
  for (int i=0;i<16;++i){ int n8=i*512+tid; v[i]=agld8(base + (size_t)(n8>>5)*1024 + (n8&31)*8); }
#pragma unroll
  for (int i=0;i<16;++i) d[i*512+tid] = v[i];
#pragma unroll
  for (int i=0;i<16;++i){ int n8=(i+16)*512+tid; v[i]=agld8(base + (size_t)(n8>>5)*1024 + (n8&31)*8); }
#pragma unroll
  for (int i=0;i<16;++i) d[(i+16)*512+tid] = v[i];
}

// ---- encoder step: block (kg,bg): 32 gate rows {g*512+kg*8+u} x 64 b ----
__device__ void encStep(const float* hin, float* hout, const float* __restrict__ eWhh,
    const float* __restrict__ wcomb, const float* __restrict__ bcomb,
    const float* __restrict__ trainT, int t, float& cE,
    int tid, int kg, int bg, float* hst)
{
  stageH(hin, bg, tid, hst);
  __syncthreads();
  const int q = tid>>6, lane = tid&63;
  const float* wr[32];
#pragma unroll
  for (int r=0;r<32;++r)
    wr[r] = eWhh + (size_t)((r>>3)*512 + kg*8 + (r&7))*HID + q*64;
  float acc[32];
#pragma unroll
  for (int r=0;r<32;++r) acc[r]=0.f;
  const float* hq = hst + (q*64)*64 + lane;
  for (int kk=0; kk<64; kk+=4) {
    float h0 = hq[(kk  )*64], h1 = hq[(kk+1)*64];
    float h2 = hq[(kk+2)*64], h3 = hq[(kk+3)*64];
#pragma unroll
    for (int r=0;r<32;++r){
      float4 w = *(const float4*)(wr[r]+kk);
      acc[r] += w.x*h0 + w.y*h1 + w.z*h2 + w.w*h3;
    }
  }
  __syncthreads();
#pragma unroll
  for (int r=0;r<32;++r) hst[(q*32+r)*64+lane] = acc[r];
  __syncthreads();
  const int u = tid>>6, b = tid&63;      // 8 x 64
  const int gb = bg*64 + b, k = kg*8 + u;
  float x0 = trainT[t*512 + gb], x1 = trainT[t*512 + 256 + gb];
  float pre[4];
#pragma unroll
  for (int g=0; g<4; ++g){
    float s = 0.f;
#pragma unroll
    for (int q8=0;q8<8;++q8) s += hst[(q8*32 + g*8 + u)*64 + b];
    int j = g*512 + k;
    pre[g] = s + wcomb[2*j]*x0 + wcomb[2*j+1]*x1 + bcomb[j];
  }
  float ii=sigf(pre[0]), ff=sigf(pre[1]), gg=tanhf(pre[2]), oo=sigf(pre[3]);
  cE = ff*cE + ii*gg;
  agst(hout + (size_t)k*256 + gb, oo*tanhf(cE));
}

// ---- decoder P: 32 GH rows (kept in LDS ghL) + 8 o1 rows (-> o1g [b][j]) ----
__device__ void phaseP(const float* hin, float* o1g, const float* __restrict__ dWhh,
    const float* __restrict__ W1, const float* __restrict__ b1,
    int tid, int kg, int bg, float* hst, float* ghL)
{
  stageH(hin, bg, tid, hst);
  __syncthreads();
  const int q = tid>>6, lane = tid&63;
  const float* wr[40];
#pragma unroll
  for (int r=0;r<32;++r)
    wr[r] = dWhh + (size_t)((r>>3)*512 + kg*8 + (r&7))*HID + q*64;
#pragma unroll
  for (int r=32;r<40;++r)
    wr[r] = W1 + (size_t)(kg*8 + (r-32))*HID + q*64;
  float acc[40];
#pragma unroll
  for (int r=0;r<40;++r) acc[r]=0.f;
  const float* hq = hst + (q*64)*64 + lane;
  for (int kk=0; kk<64; kk+=4) {
    float h0 = hq[(kk  )*64], h1 = hq[(kk+1)*64];
    float h2 = hq[(kk+2)*64], h3 = hq[(kk+3)*64];
#pragma unroll
    for (int r=0;r<40;++r){
      float4 w = *(const float4*)(wr[r]+kk);
      acc[r] += w.x*h0 + w.y*h1 + w.z*h2 + w.w*h3;
    }
  }
  __syncthreads();
#pragma unroll
  for (int r=0;r<40;++r) hst[(q*40+r)*64+lane] = acc[r];
  __syncthreads();
  const int u = tid>>6, b = tid&63;
#pragma unroll
  for (int g=0; g<4; ++g){
    float s = 0.f;
#pragma unroll
    for (int q8=0;q8<8;++q8) s += hst[(q8*40 + g*8 + u)*64 + b];
    ghL[(g*8+u)*64 + b] = s;
  }
  {
    float s = 0.f;
#pragma unroll
    for (int q8=0;q8<8;++q8) s += hst[(q8*40 + 32 + u)*64 + b];
    hst[20480 + b*8 + u] = fmaxf(s + b1[kg*8+u], 0.f);  // o1 transpose buf
  }
  __syncthreads();
  const int b2 = tid>>3, u2 = tid&7;
  agst(o1g + (size_t)(bg*64+b2)*HID + kg*8 + u2, hst[20480 + b2*8 + u2]);
}

// ---- decoder Q1 (blocks 0..127, pair of b): o2 = relu(W2.o1+b2), out row, argmax ----
__device__ void phaseQ1(int i, const float* o1g, const float* __restrict__ W2T,
    const float* __restrict__ b2, float* __restrict__ out, int* token,
    int tid, int bid, float* hst)
{
  if (bid < 128) {
    const int bA = 2*bid;
    hst[tid]       = agld(o1g + (size_t)bA*HID + tid);
    hst[512 + tid] = agld(o1g + (size_t)(bA+1)*HID + tid);
    __syncthreads();
    const int half = tid>>8, row = tid&255;
    float* amV = hst + 1024;
    int*   amI = (int*)(hst + 1536);
    float s = -3.0e38f;
    if (row < VOC) {
      const float* ov = hst + half*512;
      s = b2[row];
      for (int k=0;k<512;k+=4){
        float4 o4 = *(const float4*)(ov+k);
        s += W2T[(size_t)(k  )*256+row]*o4.x + W2T[(size_t)(k+1)*256+row]*o4.y
           + W2T[(size_t)(k+2)*256+row]*o4.z + W2T[(size_t)(k+3)*256+row]*o4.w;
      }
      s = fmaxf(s, 0.f);
      out[(size_t)i*BVO + (size_t)(bA+half)*VOC + row] = s;
    }
    amV[tid] = s; amI[tid] = row;
    __syncthreads();
    for (int off=128; off; off>>=1){
      if (row < off){
        float vo = amV[half*256+row+off]; int io = amI[half*256+row+off];
        if (vo > amV[half*256+row] ||
            (vo == amV[half*256+row] && io < amI[half*256+row])){
          amV[half*256+row]=vo; amI[half*256+row]=io;
        }
      }
      __syncthreads();
    }
    if (row == 0) agsti(&token[bA+half], amI[half*256]);
  }
}

// ---- decoder Q2: pointwise from block-local ghL + GIHT[token]; h out; c in reg ----
__device__ void phaseQ2(int first, const float* __restrict__ GIHT, const int* token,
    const int* __restrict__ target, float* hnxt, float& cD,
    int tid, int kg, int bg, const float* ghL)
{
  const int u = tid>>6, b = tid&63;
  const int gb = bg*64 + b, k = kg*8 + u;
  const int tok = first ? target[gb*TST] : agldi(token + gb);
  float pre[4];
#pragma unroll
  for (int g=0; g<4; ++g)
    pre[g] = ghL[(g*8+u)*64 + b] + GIHT[(size_t)(g*512 + k)*256 + tok];
  float ii=sigf(pre[0]), ff=sigf(pre[1]), gg=tanhf(pre[2]), oo=sigf(pre[3]);
  cD = ff*cD + ii*gg;
  agst(hnxt + (size_t)k*256 + gb, oo*tanhf(cD));
}

__global__ __launch_bounds__(NTHR, 1) void k_all(
    const float* __restrict__ train, const int* __restrict__ target,
    const float* __restrict__ fcW,  const float* __restrict__ fcb,
    const float* __restrict__ eWih, const float* __restrict__ eWhh,
    const float* __restrict__ ebih, const float* __restrict__ ebhh,
    const float* __restrict__ emb,  const float* __restrict__ dWih,
    const float* __restrict__ dWhh, const float* __restrict__ dbih,
    const float* __restrict__ dbhh, const float* __restrict__ W1,
    const float* __restrict__ b1,   const float* __restrict__ W2,
    const float* __restrict__ b2,   float* __restrict__ out,
    void* __restrict__ ws)
{
  __shared__ float hst[32768];   // 128KB: h stage / partials / o1t / Q1 scratch
  __shared__ float ghL[2048];    // 8KB: GH[32 rows][64 b], survives P->Q2

  int* bar     = (int*)ws;              // 32768 ints, host-memset 0
  float* fws   = (float*)ws + 32768;
  float* wcomb = fws;                   // 4096
  float* bcomb = wcomb + 4096;          // 2048
  float* GIHT  = bcomb + 2048;          // 524288  [j][256] (v padded)
  float* W2T   = GIHT + 524288;         // 131072  [k][256] (row padded)
  float* embT  = W2T + 131072;          // 65536   [k][256] (v padded)
  float* trainT= embT + 65536;          // 102400  [t][f][256]
  float* hA    = trainT + 102400;       // 131072  [k][b]
  float* hB    = hA + 131072;           // 131072
  float* o1g   = hB + 131072;           // 131072  [b][j]
  int* token   = (int*)(o1g + 131072);  // 256

  const int tid = threadIdx.x, bid = blockIdx.x;
  const int kg = bid >> 2, bg = bid & 3;
  int ep = 1;

  // ============== pre-phase A: tables (agent stores) ==============
  {
    int tg = bid*NTHR + tid;            // 0..131071
    agst(&hA[tg], 0.f);
    if (tg < BVO) out[tg] = 0.f;        // plain; unique writer
    if (tg < SEQ*2*NB) {
      int t = tg>>9, f = (tg>>8)&1, b = tg&255;
      agst(&trainT[tg], train[((size_t)b*SEQ + t)*2 + f]);
    }
    if (tg < G4) {
      const float* wrow = eWih + (size_t)tg*EMBD;
      float s0=0.f, s1=0.f, sb=0.f;
      for (int k2=0; k2<EMBD; k2+=4) {
        float4 w4 = *(const float4*)(wrow + k2);
        s0 += w4.x*fcW[2*k2]   + w4.y*fcW[2*k2+2] + w4.z*fcW[2*k2+4] + w4.w*fcW[2*k2+6];
        s1 += w4.x*fcW[2*k2+1] + w4.y*fcW[2*k2+3] + w4.z*fcW[2*k2+5] + w4.w*fcW[2*k2+7];
        sb += w4.x*fcb[k2]     + w4.y*fcb[k2+1]   + w4.z*fcb[k2+2]   + w4.w*fcb[k2+3];
      }
      agst(&wcomb[2*tg], s0);
      agst(&wcomb[2*tg+1], s1);
      agst(&bcomb[tg], sb + ebih[tg] + ebhh[tg]);
    }
    { // W2T[k][r] = W2[r][k]
      int k = tg>>8, r = tg&255;
      agst(&W2T[tg], (r < VOC) ? W2[(size_t)r*HID + k] : 0.f);
    }
    if (tg < 65536) { // embT[k][v] = emb[v][k]
      int k = tg>>8, v = tg&255;
      agst(&embT[tg], (v < VOC) ? emb[(size_t)v*EMBD + k] : 0.f);
    }
  }
  gsync(bar, ep); ++ep;

  // ============== pre-phase B: GIHT[j][v] = dWih[j].emb[v] + biases ==============
  {
    int j0 = bid*8;
    for (int p=0; p<4; ++p) {
      int jbase = j0 + 2*p;
      hst[tid] = dWih[(size_t)(jbase + (tid>>8))*EMBD + (tid&255)];
      __syncthreads();
      int jj = tid>>8, v = tid&255;
      int j = jbase + jj;
      float s = dbih[j] + dbhh[j];
      for (int k=0;k<EMBD;++k)
        s += hst[jj*256 + k] * agld(embT + (size_t)k*256 + v);
      agst(&GIHT[(size_t)j*256 + v], s);
      __syncthreads();
    }
  }
  gsync(bar, ep); ++ep;
  // one-time heavy acquire: invalidate L1/L2 so all ws tables are safely
  // cacheable via normal loads from here on (r2's mistake was doing this per-sync)
  __builtin_amdgcn_fence(__ATOMIC_ACQUIRE, "agent");
  __syncthreads();

  // ============== encoder: 200 steps, c in register ==============
  float c = 0.f;
  {
    const float* hin = hA; float* hout = hB;
    for (int t=0; t<SEQ; ++t) {
      encStep(hin, hout, eWhh, wcomb, bcomb, trainT, t, c, tid, kg, bg, hst);
      gsync(bar, ep); ++ep;
      const float* tmp = hin; hin = hout; hout = (float*)tmp;
    }
  }
  // h_enc in hA (200 even steps); c = encoder final c for this thread's (k,b)

  // ============== decoder ==============
  phaseP(hA, o1g, dWhh, W1, b1, tid, kg, bg, hst, ghL);
  gsync(bar, ep); ++ep;
  phaseQ2(1, GIHT, token, target, hB, c, tid, kg, bg, ghL);   // h_1 -> hB
  gsync(bar, ep); ++ep;
  for (int i=1; i<TST; ++i) {
    const float* hcur = (i&1) ? hB : hA;
    float* hnxt      = (i&1) ? hA : hB;
    phaseP(hcur, o1g, dWhh, W1, b1, tid, kg, bg, hst, ghL);
    gsync(bar, ep); ++ep;
    phaseQ1(i, o1g, W2T, b2, out, token, tid, bid, hst);
    gsync(bar, ep); ++ep;
    if (i < TST-1) {
      phaseQ2(0, GIHT, token, target, hnxt, c, tid, kg, bg, ghL);
      gsync(bar, ep); ++ep;
    }
  }
}

extern "C" void kernel_launch(void* const* d_in, const int* in_sizes, int n_in,
                              void* d_out, int out_size, void* d_ws, size_t ws_size,
                              hipStream_t stream) {
  const float* train = (const float*)d_in[0];
  const int*   target= (const int*)  d_in[1];
  const float* fcW   = (const float*)d_in[2];
  const float* fcb   = (const float*)d_in[3];
  const float* eWih  = (const float*)d_in[4];
  const float* eWhh  = (const float*)d_in[5];
  const float* ebih  = (const float*)d_in[6];
  const float* ebhh  = (const float*)d_in[7];
  const float* emb   = (const float*)d_in[8];
  const float* dWih  = (const float*)d_in[9];
  const float* dWhh  = (const float*)d_in[10];
  const float* dbih  = (const float*)d_in[11];
  const float* dbhh  = (const float*)d_in[12];
  const float* W1    = (const float*)d_in[13];
  const float* b1    = (const float*)d_in[14];
  const float* W2    = (const float*)d_in[15];
  const float* b2    = (const float*)d_in[16];
  float* out = (float*)d_out;
  void* ws = d_ws;

  // floats after bar: 4096+2048+524288+131072+65536+102400+3*131072+256(int)
  size_t need = (size_t)32768*4 + (size_t)(1222656 + 256)*4;   // ~5.0 MB
  if (ws_size < need) return;  // fail visibly

  hipMemsetAsync(d_ws, 0, 32768*sizeof(int), stream);  // barrier slots

  void* args[] = { (void*)&train, (void*)&target, (void*)&fcW, (void*)&fcb,
                   (void*)&eWih, (void*)&eWhh, (void*)&ebih, (void*)&ebhh,
                   (void*)&emb, (void*)&dWih, (void*)&dWhh, (void*)&dbih,
                   (void*)&dbhh, (void*)&W1, (void*)&b1, (void*)&W2,
                   (void*)&b2, (void*)&out, (void*)&ws };
  hipError_t err = hipLaunchCooperativeKernel(
      reinterpret_cast<void*>(k_all), dim3(NBLK), dim3(NTHR), args, 0, stream);
  if (err != hipSuccess) {
    // fallback: plain launch; 136KB LDS forces 1 block/CU -> 256 blocks co-resident.
    k_all<<<dim3(NBLK), dim3(NTHR), 0, stream>>>(
        train, target, fcW, fcb, eWih, eWhh, ebih, ebhh, emb, dWih, dWhh,
        dbih, dbhh, W1, b1, W2, b2, out, ws);
  }
}

// Round 6
// 17071.962 us; speedup vs baseline: 1.9479x; 1.0326x over previous
//
#include <hip/hip_runtime.h>
#include <math.h>

// Persistent cooperative seq2seq, round 6.
// vs r5: (1) 64-party bg-local flat barriers (4 independent groups) replace
// the 256-party two-hop barrier; (2) decoder fused to 2 phases/step (GH via
// global [b][j], token stays in-block) -> ~502 epochs total; (3) staging via
// 16B sc1 inline-asm loads (half the uncached requests); (4) LDS strides
// re-derived for [b][k] layout (516 h-tile, 65 partials).

#define NBLK 256
#define NTHR 512
#define SEQ  200
#define TST  150
#define HID  512
#define G4   2048
#define VOC  231
#define EMBD 256
#define NB   256
#define BVO  (NB*VOC)   // 59136
#define HSTR 516        // LDS h stride (floats): bank-floor for b128 r/w
#define PSTR 65         // LDS partial stride: conflict-free reduce

typedef float f32x4 __attribute__((ext_vector_type(4)));

__device__ __forceinline__ float sigf(float x){ return 1.0f/(1.0f+expf(-x)); }

__device__ __forceinline__ float agld(const float* p){
  return __hip_atomic_load((float*)p, __ATOMIC_RELAXED, __HIP_MEMORY_SCOPE_AGENT);
}
__device__ __forceinline__ void agst(float* p, float v){
  __hip_atomic_store(p, v, __ATOMIC_RELAXED, __HIP_MEMORY_SCOPE_AGENT);
}

// ---- global barrier (pre-phase only): r5's two-stage version ----
__device__ __forceinline__ void gsync(int* bar, int e) {
  __syncthreads();
  if (threadIdx.x == 0)
    __hip_atomic_store(&bar[blockIdx.x*64], e, __ATOMIC_RELAXED, __HIP_MEMORY_SCOPE_AGENT);
  if (blockIdx.x == 0) {
    if (threadIdx.x < NBLK) {
      while (__hip_atomic_load(&bar[threadIdx.x*64], __ATOMIC_RELAXED,
                               __HIP_MEMORY_SCOPE_AGENT) < e)
        __builtin_amdgcn_s_sleep(1);
    }
    __syncthreads();
    if (threadIdx.x < 8)
      __hip_atomic_store(&bar[16384 + threadIdx.x*64], e, __ATOMIC_RELAXED,
                         __HIP_MEMORY_SCOPE_AGENT);
  } else {
    if (threadIdx.x == 0) {
      while (__hip_atomic_load(&bar[16384 + (blockIdx.x & 7)*64], __ATOMIC_RELAXED,
                               __HIP_MEMORY_SCOPE_AGENT) < e)
        __builtin_amdgcn_s_sleep(1);
    }
    __syncthreads();
  }
}

// ---- bg-local 64-party flat barrier: 1 store + 1 wave-wide poll ----
__device__ __forceinline__ void bsync(int* bar, int bg, int kg, int e) {
  __syncthreads();   // drains each wave's vmcnt -> all sc1 stores acked at L3
  if (threadIdx.x == 0)
    __hip_atomic_store(&bar[32768 + (bg*64 + kg)*64], e, __ATOMIC_RELAXED,
                       __HIP_MEMORY_SCOPE_AGENT);
  if (threadIdx.x < 64) {
    const int* slot = &bar[32768 + (bg*64 + (int)threadIdx.x)*64];
    while (__hip_atomic_load((int*)slot, __ATOMIC_RELAXED,
                             __HIP_MEMORY_SCOPE_AGENT) < e)
      __builtin_amdgcn_s_sleep(1);
  }
  __syncthreads();
}

// ---- stage h[bg slice][512] (global [b][k], sc1) -> hst[b][HSTR] via 16B asm loads ----
__device__ __forceinline__ void stageH(const float* base, int tid, float* hst) {
  f32x4 v[16];
  const float* p0 = base + (size_t)(tid >> 7)*HID + (tid & 127)*4;
#pragma unroll
  for (int i = 0; i < 16; ++i) {
    const float* p = p0 + (size_t)i*2048;   // +4 b-rows per step
    asm volatile("global_load_dwordx4 %0, %1, off sc1"
                 : "=v"(v[i]) : "v"(p) : "memory");
  }
  asm volatile("s_waitcnt vmcnt(0)" ::: "memory");
  __builtin_amdgcn_sched_barrier(0);
  const int b0 = tid >> 7, c4 = (tid & 127)*4;
#pragma unroll
  for (int i = 0; i < 16; ++i)
    *(f32x4*)&hst[(b0 + i*4)*HSTR + c4] = v[i];
}

// ---- encoder step: block (kg,bg) = 32 gate rows {g*512+kg*8+u} x 64 b ----
__device__ void encStep(const float* hin, float* hout, float* cET,
    const float* __restrict__ eWhh, const float* __restrict__ wcomb,
    const float* __restrict__ bcomb, const float* __restrict__ trainT,
    int t, int last, float& cE, int tid, int kg, int bg, float* hst)
{
  stageH(hin + (size_t)bg*64*HID, tid, hst);
  __syncthreads();
  const int q = tid >> 6, lane = tid & 63;
  const float* wbase = eWhh + (size_t)(kg*8)*HID + q*64;
  float acc[32];
#pragma unroll
  for (int r = 0; r < 32; ++r) acc[r] = 0.f;
  const float* hb = &hst[lane*HSTR + q*64];
  for (int kk = 0; kk < 64; kk += 4) {
    f32x4 h4 = *(const f32x4*)&hb[kk];
#pragma unroll
    for (int r = 0; r < 32; ++r) {
      f32x4 w = *(const f32x4*)(wbase + (size_t)((r>>3)*512 + (r&7))*HID + kk);
      acc[r] += w.x*h4.x + w.y*h4.y + w.z*h4.z + w.w*h4.w;
    }
  }
  __syncthreads();
#pragma unroll
  for (int r = 0; r < 32; ++r) hst[(q*32 + r)*PSTR + lane] = acc[r];
  __syncthreads();
  const int b2 = tid >> 3, u = tid & 7;
  const int gb = bg*64 + b2, k = kg*8 + u;
  float x0 = trainT[t*512 + gb], x1 = trainT[t*512 + 256 + gb];
  float pre[4];
#pragma unroll
  for (int g = 0; g < 4; ++g) {
    float s = 0.f;
#pragma unroll
    for (int q8 = 0; q8 < 8; ++q8) s += hst[(q8*32 + g*8 + u)*PSTR + b2];
    int j = g*512 + k;
    pre[g] = s + wcomb[2*j]*x0 + wcomb[2*j+1]*x1 + bcomb[j];
  }
  float ii = sigf(pre[0]), ff = sigf(pre[1]);
  float gg = tanhf(pre[2]), oo = sigf(pre[3]);
  cE = ff*cE + ii*gg;
  agst(hout + (size_t)gb*HID + k, oo*tanhf(cE));
  if (last) agst(cET + (size_t)gb*HID + k, cE);
}

// ---- decoder P: contiguous rows j0=kg*40..+39 of [dWhh;W1]; GH->[b][j], o1->[b][k] ----
__device__ void phaseP(const float* hin, float* GH, float* o1g,
    const float* __restrict__ dWhh, const float* __restrict__ W1,
    const float* __restrict__ b1, int tid, int kg, int bg, float* hst)
{
  stageH(hin + (size_t)bg*64*HID, tid, hst);
  __syncthreads();
  const int q = tid >> 6, lane = tid & 63;
  const int j0 = kg*40;
  const float* wr[40];
#pragma unroll
  for (int r = 0; r < 40; ++r) {
    int j = j0 + r;
    wr[r] = ((j < G4) ? (dWhh + (size_t)j*HID) : (W1 + (size_t)(j - G4)*HID)) + q*64;
  }
  float acc[40];
#pragma unroll
  for (int r = 0; r < 40; ++r) acc[r] = 0.f;
  const float* hb = &hst[lane*HSTR + q*64];
  for (int kk = 0; kk < 64; kk += 4) {
    f32x4 h4 = *(const f32x4*)&hb[kk];
#pragma unroll
    for (int r = 0; r < 40; ++r) {
      f32x4 w = *(const f32x4*)(wr[r] + kk);
      acc[r] += w.x*h4.x + w.y*h4.y + w.z*h4.z + w.w*h4.w;
    }
  }
  __syncthreads();
#pragma unroll
  for (int r = 0; r < 40; ++r) hst[(q*40 + r)*PSTR + lane] = acc[r];
  __syncthreads();
  const int b2 = tid >> 3, u = tid & 7;
  const int gb = bg*64 + b2;
#pragma unroll
  for (int m = 0; m < 5; ++m) {
    int r = u*5 + m;
    float s = 0.f;
#pragma unroll
    for (int q8 = 0; q8 < 8; ++q8) s += hst[(q8*40 + r)*PSTR + b2];
    int j = j0 + r;
    if (j < G4) agst(GH + (size_t)gb*G4 + j, s);
    else        agst(o1g + (size_t)gb*HID + (j - G4), fmaxf(s + b1[j - G4], 0.f));
  }
}

// ---- decoder QZ: block = 1 batch col. o2 + out row + argmax + LSTM pointwise ----
__device__ void phaseQZ(int i, const float* GH, const float* o1g,
    const float* __restrict__ GIH, const float* __restrict__ W2T,
    const float* __restrict__ b2v, const int* __restrict__ target,
    const float* cET, float* hout, float* __restrict__ out,
    float& c0, int tid, int kg, int bg, float* smem)
{
  const int b = bg*64 + kg;
  float* o1s = smem + 33024;
  float* sP  = smem + 33536;
  float* amv = smem + 34048;
  int*   ami = (int*)(smem + 34304);
  int tok;
  if (i == 0) {
    tok = target[b*TST];                         // target[:,0]
    c0  = agld(cET + (size_t)b*HID + tid);       // encoder final c
  } else {
    o1s[tid] = agld(o1g + (size_t)b*HID + tid);
    __syncthreads();
    const int row = tid & 255, kh = tid >> 8;
    float s = 0.f;
    if (row < VOC) {
      const float* o1p = o1s + kh*256;
      const float* wp  = W2T + (size_t)kh*256*256 + row;
#pragma unroll 8
      for (int k2 = 0; k2 < 256; ++k2) s += wp[(size_t)k2*256] * o1p[k2];
    }
    sP[tid] = s;
    __syncthreads();
    if (kh == 0) {
      float o2 = -3.0e38f;
      if (row < VOC) {
        o2 = fmaxf(sP[row] + sP[256 + row] + b2v[row], 0.f);
        out[(size_t)i*BVO + (size_t)b*VOC + row] = o2;
      }
      amv[row] = o2; ami[row] = row;
    }
    __syncthreads();
    for (int off = 128; off; off >>= 1) {
      if (tid < off) {
        float vo = amv[tid + off]; int io = ami[tid + off];
        if (vo > amv[tid] || (vo == amv[tid] && io < ami[tid])) {
          amv[tid] = vo; ami[tid] = io;
        }
      }
      __syncthreads();
    }
    tok = ami[0];
    if (i == TST - 1) return;   // last output written; no further state
  }
  float pre[4];
#pragma unroll
  for (int g = 0; g < 4; ++g) {
    int j = g*512 + tid;
    pre[g] = agld(GH + (size_t)b*G4 + j) + GIH[(size_t)tok*G4 + j];
  }
  float ii = sigf(pre[0]), ff = sigf(pre[1]);
  float gg = tanhf(pre[2]), oo = sigf(pre[3]);
  c0 = ff*c0 + ii*gg;
  agst(hout + (size_t)b*HID + tid, oo*tanhf(c0));
}

__global__ __launch_bounds__(NTHR, 1) void k_all(
    const float* __restrict__ train, const int* __restrict__ target,
    const float* __restrict__ fcW,  const float* __restrict__ fcb,
    const float* __restrict__ eWih, const float* __restrict__ eWhh,
    const float* __restrict__ ebih, const float* __restrict__ ebhh,
    const float* __restrict__ emb,  const float* __restrict__ dWih,
    const float* __restrict__ dWhh, const float* __restrict__ dbih,
    const float* __restrict__ dbhh, const float* __restrict__ W1,
    const float* __restrict__ b1,   const float* __restrict__ W2,
    const float* __restrict__ b2,   float* __restrict__ out,
    void* __restrict__ ws)
{
  __shared__ float smem[35072];   // 140.3 KB: h-tile/partials + QZ scratch

  int* bar     = (int*)ws;              // 49152 ints, host-memset 0
  float* fws   = (float*)ws + 49152;
  float* wcomb = fws;                   // 4096
  float* bcomb = wcomb + 4096;          // 2048
  float* GIH   = bcomb + 2048;          // 473088  [tok][2048]
  float* W2T   = GIH + 473088;          // 131072  [k][256]
  float* trainT= W2T + 131072;          // 102400  [t][f][256]
  float* hA    = trainT + 102400;       // 131072  [b][512]
  float* hB    = hA + 131072;           // 131072
  float* cET   = hB + 131072;           // 131072  [b][512]
  float* o1g   = cET + 131072;          // 131072  [b][512]
  float* GH    = o1g + 131072;          // 524288  [b][2048]

  const int tid = threadIdx.x, bid = blockIdx.x;
  const int kg = bid >> 2, bg = bid & 3;

  // ============== pre-phase: tables (agent stores), one global sync ==============
  {
    int tg = bid*NTHR + tid;            // 0..131071
    agst(&hA[tg], 0.f);                 // h0 = 0
    if (tg < BVO) out[tg] = 0.f;        // outputs[0] = zeros (unique writer)
    if (tg < SEQ*2*NB) {
      int t = tg>>9, f = (tg>>8)&1, b = tg&255;
      agst(&trainT[tg], train[((size_t)b*SEQ + t)*2 + f]);
    }
    if (tg < G4) {                      // fold enc FC into input weights
      const float* wrow = eWih + (size_t)tg*EMBD;
      float s0=0.f, s1=0.f, sb=0.f;
      for (int k2 = 0; k2 < EMBD; k2 += 4) {
        float4 w4 = *(const float4*)(wrow + k2);
        s0 += w4.x*fcW[2*k2]   + w4.y*fcW[2*k2+2] + w4.z*fcW[2*k2+4] + w4.w*fcW[2*k2+6];
        s1 += w4.x*fcW[2*k2+1] + w4.y*fcW[2*k2+3] + w4.z*fcW[2*k2+5] + w4.w*fcW[2*k2+7];
        sb += w4.x*fcb[k2]     + w4.y*fcb[k2+1]   + w4.z*fcb[k2+2]   + w4.w*fcb[k2+3];
      }
      agst(&wcomb[2*tg], s0);
      agst(&wcomb[2*tg+1], s1);
      agst(&bcomb[tg], sb + ebih[tg] + ebhh[tg]);
    }
    { // W2T[k][r] = W2[r][k]
      int k = tg>>8, r = tg&255;
      agst(&W2T[tg], (r < VOC) ? W2[(size_t)r*HID + k] : 0.f);
    }
    __syncthreads();
    if (bid < VOC) {                    // GIH[v][j] = emb[v].dWih[j] + biases
      if (tid < EMBD) smem[tid] = emb[(size_t)bid*EMBD + tid];
      __syncthreads();
      for (int u = 0; u < 4; ++u) {
        int j = u*512 + tid;
        const float* wrow = dWih + (size_t)j*EMBD;
        float s = 0.f;
        for (int k2 = 0; k2 < EMBD; k2 += 4) {
          float4 w4 = *(const float4*)(wrow + k2);
          s += smem[k2]*w4.x + smem[k2+1]*w4.y + smem[k2+2]*w4.z + smem[k2+3]*w4.w;
        }
        agst(&GIH[(size_t)bid*G4 + j], s + dbih[j] + dbhh[j]);
      }
    }
  }
  gsync(bar, 1);
  // one-time heavy acquire: L1/L2 invalidate so ws tables are cacheable normal loads
  __builtin_amdgcn_fence(__ATOMIC_ACQUIRE, "agent");
  __syncthreads();

  int eb = 0;

  // ============== encoder: 200 steps, c in register ==============
  float cE = 0.f;
  {
    const float* hin = hA; float* hout = hB;
    for (int t = 0; t < SEQ; ++t) {
      encStep(hin, hout, cET, eWhh, wcomb, bcomb, trainT, t, t == SEQ-1,
              cE, tid, kg, bg, smem);
      bsync(bar, bg, kg, ++eb);
      const float* tmp = hin; hin = hout; hout = (float*)tmp;
    }
  }
  // h_enc in hA (even step count)

  // ============== decoder: 2 phases/step ==============
  float c0 = 0.f;
  phaseP(hA, GH, o1g, dWhh, W1, b1, tid, kg, bg, smem);
  bsync(bar, bg, kg, ++eb);
  phaseQZ(0, GH, o1g, GIH, W2T, b2, target, cET, hB, out, c0, tid, kg, bg, smem);
  bsync(bar, bg, kg, ++eb);
  for (int i = 1; i < TST; ++i) {
    const float* cur = (i & 1) ? hB : hA;
    float* nxt       = (i & 1) ? hA : hB;
    phaseP(cur, GH, o1g, dWhh, W1, b1, tid, kg, bg, smem);
    bsync(bar, bg, kg, ++eb);
    phaseQZ(i, GH, o1g, GIH, W2T, b2, target, cET, nxt, out, c0, tid, kg, bg, smem);
    if (i < TST-1) bsync(bar, bg, kg, ++eb);
  }
}

extern "C" void kernel_launch(void* const* d_in, const int* in_sizes, int n_in,
                              void* d_out, int out_size, void* d_ws, size_t ws_size,
                              hipStream_t stream) {
  const float* train = (const float*)d_in[0];
  const int*   target= (const int*)  d_in[1];
  const float* fcW   = (const float*)d_in[2];
  const float* fcb   = (const float*)d_in[3];
  const float* eWih  = (const float*)d_in[4];
  const float* eWhh  = (const float*)d_in[5];
  const float* ebih  = (const float*)d_in[6];
  const float* ebhh  = (const float*)d_in[7];
  const float* emb   = (const float*)d_in[8];
  const float* dWih  = (const float*)d_in[9];
  const float* dWhh  = (const float*)d_in[10];
  const float* dbih  = (const float*)d_in[11];
  const float* dbhh  = (const float*)d_in[12];
  const float* W1    = (const float*)d_in[13];
  const float* b1    = (const float*)d_in[14];
  const float* W2    = (const float*)d_in[15];
  const float* b2    = (const float*)d_in[16];
  float* out = (float*)d_out;
  void* ws = d_ws;

  // bar 49152 ints + 1,761,280 floats ~= 7.24 MB
  size_t need = (size_t)49152*4 + (size_t)1761280*4;
  if (ws_size < need) return;  // fail visibly

  hipMemsetAsync(d_ws, 0, 49152*sizeof(int), stream);  // barrier slots

  void* args[] = { (void*)&train, (void*)&target, (void*)&fcW, (void*)&fcb,
                   (void*)&eWih, (void*)&eWhh, (void*)&ebih, (void*)&ebhh,
                   (void*)&emb, (void*)&dWih, (void*)&dWhh, (void*)&dbih,
                   (void*)&dbhh, (void*)&W1, (void*)&b1, (void*)&W2,
                   (void*)&b2, (void*)&out, (void*)&ws };
  hipError_t err = hipLaunchCooperativeKernel(
      reinterpret_cast<void*>(k_all), dim3(NBLK), dim3(NTHR), args, 0, stream);
  if (err != hipSuccess) {
    // fallback: plain launch; 140KB LDS -> 1 block/CU -> 256 blocks co-resident.
    k_all<<<dim3(NBLK), dim3(NTHR), 0, stream>>>(
        train, target, fcW, fcb, eWih, eWhh, ebih, ebhh, emb, dWih, dWhh,
        dbih, dbhh, W1, b1, W2, b2, out, ws);
  }
}

// Round 9
// 16242.921 us; speedup vs baseline: 2.0473x; 1.0510x over previous
//
#include <hip/hip_runtime.h>
#include <math.h>

// Persistent cooperative seq2seq, round 9.
// No inline-asm memory ops (r8 crashed on an asm register-overlap). Proven
// primitives only: __hip_atomic_* 4B/8B sc1 traffic, plain LDS, shfl reduce.
// W LDS-resident; h LDS-staged double-buffered (T14 issue-early/write-late in
// plain C); in-wave kq-split + shfl_xor reduce (no LDS partials); c-state in
// registers encoder->decoder (same thread owns same (unit, 4 cols) everywhere);
// decoder P/Q/Z with gh held in registers across barriers.

#define NBLK 256
#define NTHR 512
#define SEQ  200
#define TST  150
#define HID  512
#define G4   2048
#define VOC  231
#define EMBD 256
#define NB   256
#define BVO  (NB*VOC)
#define WROW 520        // LDS W row stride (floats), 16B-aligned

typedef float f32x4 __attribute__((ext_vector_type(4)));

__device__ __forceinline__ float sigf(float x){ return 1.0f/(1.0f+expf(-x)); }

__device__ __forceinline__ float agld(const float* p){
  return __hip_atomic_load((float*)p, __ATOMIC_RELAXED, __HIP_MEMORY_SCOPE_AGENT);
}
__device__ __forceinline__ void agst(float* p, float v){
  __hip_atomic_store(p, v, __ATOMIC_RELAXED, __HIP_MEMORY_SCOPE_AGENT);
}
__device__ __forceinline__ unsigned long long agld8(const float* p){
  return __hip_atomic_load((unsigned long long*)p, __ATOMIC_RELAXED,
                           __HIP_MEMORY_SCOPE_AGENT);
}
__device__ __forceinline__ int agldi(const int* p){
  return __hip_atomic_load((int*)p, __ATOMIC_RELAXED, __HIP_MEMORY_SCOPE_AGENT);
}
__device__ __forceinline__ void agsti(int* p, int v){
  __hip_atomic_store(p, v, __ATOMIC_RELAXED, __HIP_MEMORY_SCOPE_AGENT);
}

// ---- global barrier (pre-phase only) ----
__device__ __forceinline__ void gsync(int* bar, int e) {
  __syncthreads();
  if (threadIdx.x == 0)
    __hip_atomic_store(&bar[blockIdx.x*64], e, __ATOMIC_RELAXED, __HIP_MEMORY_SCOPE_AGENT);
  if (blockIdx.x == 0) {
    if (threadIdx.x < NBLK) {
      while (__hip_atomic_load(&bar[threadIdx.x*64], __ATOMIC_RELAXED,
                               __HIP_MEMORY_SCOPE_AGENT) < e)
        __builtin_amdgcn_s_sleep(1);
    }
    __syncthreads();
    if (threadIdx.x < 8)
      __hip_atomic_store(&bar[16384 + threadIdx.x*64], e, __ATOMIC_RELAXED,
                         __HIP_MEMORY_SCOPE_AGENT);
  } else {
    if (threadIdx.x == 0) {
      while (__hip_atomic_load(&bar[16384 + (blockIdx.x & 7)*64], __ATOMIC_RELAXED,
                               __HIP_MEMORY_SCOPE_AGENT) < e)
        __builtin_amdgcn_s_sleep(1);
    }
    __syncthreads();
  }
}

// ---- bg-local 64-party flat barrier ----
__device__ __forceinline__ void bsync(int* bar, int bg, int kg, int e) {
  __syncthreads();   // drains vmcnt: all sc1 stores acked at coherence point
  if (threadIdx.x == 0)
    __hip_atomic_store(&bar[32768 + (bg*64 + kg)*64], e, __ATOMIC_RELAXED,
                       __HIP_MEMORY_SCOPE_AGENT);
  if (threadIdx.x < 64) {
    const int* slot = &bar[32768 + (bg*64 + (int)threadIdx.x)*64];
    while (__hip_atomic_load((int*)slot, __ATOMIC_RELAXED,
                             __HIP_MEMORY_SCOPE_AGENT) < e)
      __builtin_amdgcn_s_sleep(1);
  }
  __syncthreads();
}

// ---- stage a 128-k quarter of h[k][256] (cols bg*64..+63) ----
__device__ __forceinline__ void stageIssue(const float* hin, int qidx, int bg, int tid,
                                           unsigned long long v[8]){
  const float* base = hin + (size_t)qidx*128*256 + bg*64;
#pragma unroll
  for (int n=0;n<8;++n){
    int off = n*512 + tid;                       // 0..4095 8B units
    v[n] = agld8(base + ((size_t)(off>>5))*256 + ((off&31)<<1));
  }
}
__device__ __forceinline__ void stageWrite(float* buf, int tid,
                                           const unsigned long long v[8]){
  unsigned long long* d = (unsigned long long*)buf;
#pragma unroll
  for (int n=0;n<8;++n) d[n*512+tid] = v[n];     // buf[k][64], k-local
}

// ---- encoder step: wave = unit j=kg*8+w; lane=(kq,b16); acc[4g][4b] ----
__device__ __forceinline__ void encStep(
    const float* hin, float* hout, const float* WL, float* hs,
    const float* __restrict__ pcombE, const float* __restrict__ trainT,
    int t, float cE[4], int tid, int kg, int bg, int w, int kq, int b16)
{
  float acc[4][4];
#pragma unroll
  for (int g=0;g<4;++g)
#pragma unroll
    for (int bb=0;bb<4;++bb) acc[g][bb]=0.f;
  unsigned long long v[8];
  stageIssue(hin, 0, bg, tid, v);
  stageWrite(hs, tid, v);
  __syncthreads();
  for (int q=0;q<4;++q){
    const float* buf = hs + ((q&1)<<13);
    if (q<3) stageIssue(hin, q+1, bg, tid, v);   // loads in flight during FMA
#pragma unroll
    for (int c8=0;c8<8;++c8){
      const int k0 = (kq<<5)+(c8<<2);
      const float* hb = buf + k0*64 + (b16<<2);
      f32x4 ha=*(const f32x4*)(hb),     h1=*(const f32x4*)(hb+64),
            h2=*(const f32x4*)(hb+128), h3=*(const f32x4*)(hb+192);
#pragma unroll
      for (int g=0;g<4;++g){
        f32x4 wv = *(const f32x4*)&WL[(4*w+g)*WROW + (q<<7) + k0];
#pragma unroll
        for (int bb=0;bb<4;++bb)
          acc[g][bb] += wv[0]*ha[bb] + wv[1]*h1[bb] + wv[2]*h2[bb] + wv[3]*h3[bb];
      }
    }
    if (q<3) stageWrite(hs + (((q+1)&1)<<13), tid, v);
    __syncthreads();
  }
#pragma unroll
  for (int g=0;g<4;++g)
#pragma unroll
    for (int bb=0;bb<4;++bb){
      float vv = acc[g][bb];
      vv += __shfl_xor(vv,16);
      vv += __shfl_xor(vv,32);
      acc[g][bb]=vv;
    }
  const int j = kg*8 + w;
  const int bO = bg*64 + (b16<<2);
  f32x4 pc0 = *(const f32x4*)&pcombE[j*12];
  f32x4 pc1 = *(const f32x4*)&pcombE[j*12+4];
  f32x4 pc2 = *(const f32x4*)&pcombE[j*12+8];
  f32x4 x0  = *(const f32x4*)&trainT[t*512 + bO];
  f32x4 x1  = *(const f32x4*)&trainT[t*512 + 256 + bO];
  float hres[4];
#pragma unroll
  for (int bb=0;bb<4;++bb){
    float p0 = acc[0][bb] + pc0[0]*x0[bb] + pc1[0]*x1[bb] + pc2[0];
    float p1 = acc[1][bb] + pc0[1]*x0[bb] + pc1[1]*x1[bb] + pc2[1];
    float p2 = acc[2][bb] + pc0[2]*x0[bb] + pc1[2]*x1[bb] + pc2[2];
    float p3 = acc[3][bb] + pc0[3]*x0[bb] + pc1[3]*x1[bb] + pc2[3];
    float ii=sigf(p0), ff=sigf(p1), gg=tanhf(p2), oo=sigf(p3);
    cE[bb] = ff*cE[bb] + ii*gg;
    hres[bb] = oo*tanhf(cE[bb]);
  }
  // lane stores column b16*4+kq -> 64 lanes cover 256B contiguous
  float sv = (kq==0)?hres[0]:(kq==1)?hres[1]:(kq==2)?hres[2]:hres[3];
  agst(&hout[(size_t)j*256 + bO + kq], sv);
}

// ---- decoder P: wave = unit u; 4 gh rows (stay in regs) + 1 o1 row ----
__device__ __forceinline__ void phaseP(
    const float* hin, float* o1T, const float* WL, float* hs,
    const float* __restrict__ b1, float gh[4][4],
    int tid, int kg, int bg, int w, int kq, int b16)
{
  float acc[5][4];
#pragma unroll
  for (int r=0;r<5;++r)
#pragma unroll
    for (int bb=0;bb<4;++bb) acc[r][bb]=0.f;
  unsigned long long v[8];
  stageIssue(hin, 0, bg, tid, v);
  stageWrite(hs, tid, v);
  __syncthreads();
  for (int q=0;q<4;++q){
    const float* buf = hs + ((q&1)<<13);
    if (q<3) stageIssue(hin, q+1, bg, tid, v);
#pragma unroll
    for (int c8=0;c8<8;++c8){
      const int k0 = (kq<<5)+(c8<<2);
      const float* hb = buf + k0*64 + (b16<<2);
      f32x4 ha=*(const f32x4*)(hb),     h1=*(const f32x4*)(hb+64),
            h2=*(const f32x4*)(hb+128), h3=*(const f32x4*)(hb+192);
#pragma unroll
      for (int r=0;r<5;++r){
        f32x4 wv = *(const f32x4*)&WL[(5*w+r)*WROW + (q<<7) + k0];
#pragma unroll
        for (int bb=0;bb<4;++bb)
          acc[r][bb] += wv[0]*ha[bb] + wv[1]*h1[bb] + wv[2]*h2[bb] + wv[3]*h3[bb];
      }
    }
    if (q<3) stageWrite(hs + (((q+1)&1)<<13), tid, v);
    __syncthreads();
  }
#pragma unroll
  for (int r=0;r<5;++r)
#pragma unroll
    for (int bb=0;bb<4;++bb){
      float vv = acc[r][bb];
      vv += __shfl_xor(vv,16);
      vv += __shfl_xor(vv,32);
      acc[r][bb]=vv;
    }
#pragma unroll
  for (int g=0;g<4;++g)
#pragma unroll
    for (int bb=0;bb<4;++bb) gh[g][bb] = acc[g][bb];
  const int u = kg*8 + w;
  const float b1u = b1[u];
  float o0 = fmaxf(acc[4][0]+b1u,0.f), o1v = fmaxf(acc[4][1]+b1u,0.f);
  float o2v = fmaxf(acc[4][2]+b1u,0.f), o3 = fmaxf(acc[4][3]+b1u,0.f);
  float sv = (kq==0)?o0:(kq==1)?o1v:(kq==2)?o2v:o3;
  agst(&o1T[(size_t)u*256 + bg*64 + (b16<<2) + kq], sv);
}

// ---- decoder Q (kg<16, 4 cols/block): o2 + out row + argmax -> token ----
__device__ __forceinline__ void phaseQ(int i, const float* o1T,
    const float* __restrict__ W2T, const float* __restrict__ b2v,
    float* __restrict__ out, int* token, float* ovl, int tid, int kg, int bg)
{
  if (kg >= 16) return;
  float* o1s = ovl;            // [4][512]
  float* sP  = ovl + 2048;     // [4][512]
  float* amv = ovl + 4096;     // [4][256]
  int*   ami = (int*)(ovl + 5120);
  const int c0 = bg*64 + (kg<<2);
#pragma unroll
  for (int cc=0;cc<4;++cc)
    o1s[cc*512+tid] = agld(&o1T[(size_t)tid*256 + c0+cc]);
  __syncthreads();
  {
    const int kh = tid>>8, row = tid&255;
    const float* wp = W2T + ((size_t)kh<<16) + row;
    const float* op = o1s + (kh<<8);
    float s0=0.f,s1=0.f,s2=0.f,s3=0.f;
#pragma unroll 8
    for (int k2=0;k2<256;++k2){
      float wv = wp[(size_t)k2<<8];
      s0 += wv*op[k2];      s1 += wv*op[512+k2];
      s2 += wv*op[1024+k2]; s3 += wv*op[1536+k2];
    }
    sP[(kh<<8)+row]        = s0;
    sP[512 + (kh<<8)+row]  = s1;
    sP[1024 + (kh<<8)+row] = s2;
    sP[1536 + (kh<<8)+row] = s3;
  }
  __syncthreads();
  {
    const int half = tid>>8, row = tid&255;
#pragma unroll
    for (int cp=0;cp<2;++cp){
      int cc = (half<<1) + cp;
      float o2 = -3.0e38f;
      if (row < VOC){
        o2 = fmaxf(sP[cc*512+row] + sP[cc*512+256+row] + b2v[row], 0.f);
        out[(size_t)i*BVO + (size_t)(c0+cc)*VOC + row] = o2;
      }
      amv[cc*256+row] = o2; ami[cc*256+row] = row;
    }
  }
  __syncthreads();
#pragma unroll
  for (int lv=7; lv>=0; --lv){
    const int off = 1<<lv;
    if (tid < (off<<2)){
      const int cc = tid>>lv, r = tid & (off-1);
      const int ia = cc*256+r, ib = ia+off;
      float vo = amv[ib]; int io = ami[ib];
      if (vo > amv[ia] || (vo==amv[ia] && io<ami[ia])){ amv[ia]=vo; ami[ia]=io; }
    }
    __syncthreads();
  }
  if (tid < 4) agsti(&token[c0+tid], ami[tid<<8]);
}

// ---- decoder Z: pointwise from reg-gh + GIHT[j][tok]; c in regs; h store ----
__device__ __forceinline__ void phaseZ(int boot, const int* __restrict__ target,
    const int* token, const float* __restrict__ GIHT, float* hdst,
    const float gh[4][4], float cE[4], int kg, int bg, int w, int kq, int b16)
{
  const int u = kg*8 + w;
  const int bO = bg*64 + (b16<<2);
  int tok0 = boot ? target[(bO+0)*TST] : agldi(&token[bO+0]);
  int tok1 = boot ? target[(bO+1)*TST] : agldi(&token[bO+1]);
  int tok2 = boot ? target[(bO+2)*TST] : agldi(&token[bO+2]);
  int tok3 = boot ? target[(bO+3)*TST] : agldi(&token[bO+3]);
  int tok[4] = {tok0,tok1,tok2,tok3};
  float hres[4];
#pragma unroll
  for (int bb=0;bb<4;++bb){
    float p0 = gh[0][bb] + GIHT[(size_t)((0<<9)+u)*256 + tok[bb]];
    float p1 = gh[1][bb] + GIHT[(size_t)((1<<9)+u)*256 + tok[bb]];
    float p2 = gh[2][bb] + GIHT[(size_t)((2<<9)+u)*256 + tok[bb]];
    float p3 = gh[3][bb] + GIHT[(size_t)((3<<9)+u)*256 + tok[bb]];
    float ii=sigf(p0), ff=sigf(p1), gg=tanhf(p2), oo=sigf(p3);
    cE[bb] = ff*cE[bb] + ii*gg;
    hres[bb] = oo*tanhf(cE[bb]);
  }
  float sv = (kq==0)?hres[0]:(kq==1)?hres[1]:(kq==2)?hres[2]:hres[3];
  agst(&hdst[(size_t)u*256 + bO + kq], sv);
}

__global__ __launch_bounds__(NTHR, 1) void k_all(
    const float* __restrict__ train, const int* __restrict__ target,
    const float* __restrict__ fcW,  const float* __restrict__ fcb,
    const float* __restrict__ eWih, const float* __restrict__ eWhh,
    const float* __restrict__ ebih, const float* __restrict__ ebhh,
    const float* __restrict__ emb,  const float* __restrict__ dWih,
    const float* __restrict__ dWhh, const float* __restrict__ dbih,
    const float* __restrict__ dbhh, const float* __restrict__ W1,
    const float* __restrict__ b1,   const float* __restrict__ W2,
    const float* __restrict__ b2,   float* __restrict__ out,
    void* __restrict__ ws)
{
  __shared__ float smem[37184];       // WL [40][520]=20800 | hs 2x8192 (Q overlays hs)
  float* WL  = smem;
  float* hs  = smem + 20800;
  float* ovl = smem + 20800;          // Q scratch overlays hs (disjoint in time)

  int*   bar    = (int*)ws;           // 49152 ints, host-memset 0
  float* fws    = (float*)ws + 49152;
  float* pcombE = fws;                // 6144   [u][12]
  float* trainT = pcombE + 6144;      // 102400 [t][f][256]
  float* W2T    = trainT + 102400;    // 131072 [k][256] (row>=VOC zero)
  float* GIHT   = W2T + 131072;       // 524288 [j][256tok]
  float* hTA    = GIHT + 524288;      // 131072 [k][256]
  float* hTB    = hTA + 131072;       // 131072
  float* o1T    = hTB + 131072;       // 131072 [k][256]
  int*   token  = (int*)(o1T + 131072); // 256

  const int tid = threadIdx.x, bid = blockIdx.x;
  const int kg = bid>>2, bg = bid&3;
  const int w = tid>>6, lane = tid&63, kq = lane>>4, b16 = lane&15;

  // ================= pre-phase (agent stores) =================
  {
    int tg = bid*NTHR + tid;          // 0..131071
    agst(&hTA[tg], 0.f);              // h0 = 0
    if (tg < BVO) out[tg] = 0.f;      // outputs row 0 = zeros
    if (tg < SEQ*2*NB){
      int t = tg>>9, f = (tg>>8)&1, b = tg&255;
      agst(&trainT[tg], train[((size_t)b*SEQ + t)*2 + f]);
    }
    { int k = tg>>8, r = tg&255;
      agst(&W2T[tg], (r < VOC) ? W2[(size_t)r*HID + k] : 0.f); }
    if (tg < G4){                     // fold enc FC into input weights
      const float* wrow = eWih + (size_t)tg*EMBD;
      float s0=0.f, s1=0.f, sb=0.f;
      for (int k2=0;k2<EMBD;k2+=4){
        f32x4 w4 = *(const f32x4*)(wrow + k2);
        s0 += w4[0]*fcW[2*k2]   + w4[1]*fcW[2*k2+2] + w4[2]*fcW[2*k2+4] + w4[3]*fcW[2*k2+6];
        s1 += w4[0]*fcW[2*k2+1] + w4[1]*fcW[2*k2+3] + w4[2]*fcW[2*k2+5] + w4[3]*fcW[2*k2+7];
        sb += w4[0]*fcb[k2]     + w4[1]*fcb[k2+1]   + w4[2]*fcb[k2+2]   + w4[3]*fcb[k2+3];
      }
      int g = tg>>9, u = tg&511;
      agst(&pcombE[u*12 + g],     s0);
      agst(&pcombE[u*12 + 4 + g], s1);
      agst(&pcombE[u*12 + 8 + g], sb + ebih[tg] + ebhh[tg]);
    }
    // GIHT[j][tok] = dWih[j].emb[tok] + dbih[j] + dbhh[j]; block owns 8 j rows
    for (int p=0;p<4;++p){
      int idx = p*512 + tid;          // 0..2047
      int jj = idx>>8, tk = idx&255;
      int j = bid*8 + jj;
      float s = 0.f;
      if (tk < VOC){
        const float* wr = dWih + (size_t)j*EMBD;
        const float* er = emb + (size_t)tk*EMBD;
        for (int k2=0;k2<EMBD;k2+=4){
          f32x4 w4 = *(const f32x4*)(wr + k2);
          f32x4 e4 = *(const f32x4*)(er + k2);
          s += w4[0]*e4[0] + w4[1]*e4[1] + w4[2]*e4[2] + w4[3]*e4[3];
        }
        s += dbih[j] + dbhh[j];
      }
      agst(&GIHT[(size_t)j*256 + tk], s);
    }
  }
  gsync(bar, 1);
  __builtin_amdgcn_fence(__ATOMIC_ACQUIRE, "agent");  // one-time L1/L2 inval
  __syncthreads();

  // ---- encoder weights -> LDS (rows j=g*512+kg*8+w, layout [w*4+g][520]) ----
  for (int r=0;r<32;++r){
    int ww = r>>2, g = r&3;
    WL[r*WROW + tid] = eWhh[((size_t)((g<<9) + kg*8 + ww))*HID + tid];
  }
  __syncthreads();

  int eb = 0;
  float cE[4] = {0.f,0.f,0.f,0.f};
  {
    const float* hin = hTA; float* hout = hTB;
    for (int t=0;t<SEQ;++t){
      encStep(hin, hout, WL, hs, pcombE, trainT, t, cE, tid, kg, bg, w, kq, b16);
      bsync(bar, bg, kg, ++eb);
      const float* tmp = hin; hin = hout; hout = (float*)tmp;
    }
  }
  // h_enc in hTA (200 steps, even); cE = encoder final c for (u, 4 cols)

  // ---- decoder weights -> LDS (rows: 4 dWhh gates of u + W1 row u) ----
  for (int r=0;r<40;++r){
    int ww = r/5, ri = r%5;
    const float* src = (ri<4) ? dWhh + ((size_t)((ri<<9) + kg*8 + ww))*HID
                              : W1   + ((size_t)(kg*8 + ww))*HID;
    WL[r*WROW + tid] = src[tid];
  }
  __syncthreads();

  float gh[4][4];
  // bootstrap: P(h_enc) -> gh; Z(tok=target[:,0], c carried in regs) -> h_1
  phaseP(hTA, o1T, WL, hs, b1, gh, tid, kg, bg, w, kq, b16);
  bsync(bar, bg, kg, ++eb);
  phaseZ(1, target, token, GIHT, hTB, gh, cE, kg, bg, w, kq, b16);
  bsync(bar, bg, kg, ++eb);

  for (int i=1;i<TST;++i){
    const float* hsrc = (i&1) ? hTB : hTA;
    float* hdst       = (i&1) ? hTA : hTB;
    phaseP(hsrc, o1T, WL, hs, b1, gh, tid, kg, bg, w, kq, b16);
    bsync(bar, bg, kg, ++eb);
    phaseQ(i, o1T, W2T, b2, out, token, ovl, tid, kg, bg);
    if (i == TST-1) break;            // last output row written; done
    bsync(bar, bg, kg, ++eb);
    phaseZ(0, target, token, GIHT, hdst, gh, cE, kg, bg, w, kq, b16);
    bsync(bar, bg, kg, ++eb);
  }
}

extern "C" void kernel_launch(void* const* d_in, const int* in_sizes, int n_in,
                              void* d_out, int out_size, void* d_ws, size_t ws_size,
                              hipStream_t stream) {
  const float* train = (const float*)d_in[0];
  const int*   target= (const int*)  d_in[1];
  const float* fcW   = (const float*)d_in[2];
  const float* fcb   = (const float*)d_in[3];
  const float* eWih  = (const float*)d_in[4];
  const float* eWhh  = (const float*)d_in[5];
  const float* ebih  = (const float*)d_in[6];
  const float* ebhh  = (const float*)d_in[7];
  const float* emb   = (const float*)d_in[8];
  const float* dWih  = (const float*)d_in[9];
  const float* dWhh  = (const float*)d_in[10];
  const float* dbih  = (const float*)d_in[11];
  const float* dbhh  = (const float*)d_in[12];
  const float* W1    = (const float*)d_in[13];
  const float* b1    = (const float*)d_in[14];
  const float* W2    = (const float*)d_in[15];
  const float* b2    = (const float*)d_in[16];
  float* out = (float*)d_out;
  void* ws = d_ws;

  // bar 49152 ints + 1,157,120 floats + 256 ints ~= 4.83 MB
  size_t need = (size_t)(49152 + 1157120 + 256)*4;
  if (ws_size < need) return;  // fail visibly

  (void)hipMemsetAsync(d_ws, 0, 49152*sizeof(int), stream);  // barrier slots

  void* args[] = { (void*)&train, (void*)&target, (void*)&fcW, (void*)&fcb,
                   (void*)&eWih, (void*)&eWhh, (void*)&ebih, (void*)&ebhh,
                   (void*)&emb, (void*)&dWih, (void*)&dWhh, (void*)&dbih,
                   (void*)&dbhh, (void*)&W1, (void*)&b1, (void*)&W2,
                   (void*)&b2, (void*)&out, (void*)&ws };
  hipError_t err = hipLaunchCooperativeKernel(
      reinterpret_cast<void*>(k_all), dim3(NBLK), dim3(NTHR), args, 0, stream);
  if (err != hipSuccess) {
    // fallback: plain launch; 148KB LDS -> 1 block/CU -> 256 blocks co-resident.
    k_all<<<dim3(NBLK), dim3(NTHR), 0, stream>>>(
        train, target, fcW, fcb, eWih, eWhh, ebih, ebhh, emb, dWih, dWhh,
        dbih, dbhh, W1, b1, W2, b2, out, ws);
  }
}